// Round 3
// baseline (125.817 us; speedup 1.0000x reference)
//
#include <hip/hip_runtime.h>
#include <math.h>

#define NDET 512
#define NANG 180
#define NB   8
#define NIMG 512

// ---- ws layout in floats ----
#define WS_HR 0                       // 512 floats: Ram-Lak spatial kernel h
#define WS_CA 512                     // 180 floats: cos(theta)*255.5/sqrt2
#define WS_SA 768                     // 180 floats: sin(theta)*255.5/sqrt2
#define WS_FG 1024                    // fglob[a][d][b]: 180*512*8 floats
#define WS_BP (1024 + NANG*NDET*NB)   // bp image [8][512][512]

__device__ __forceinline__ void gld_lds16(const void* g, void* l) {
    __builtin_amdgcn_global_load_lds((__attribute__((address_space(1))) void*)g,
                                     (__attribute__((address_space(3))) void*)l,
                                     16, 0, 0);
}

// ---------------- kernel 1: tables (h, cos/sin) ----------------
// h[n] = (1/512)*[ 2*sum_{k=1}^{255} (k/512) cos(2*pi*k*n/512) + 0.5*cos(pi*n) ]
__global__ __launch_bounds__(64) void k_tables(float* ws) {
    const int blk  = blockIdx.x;
    const int lane = threadIdx.x;
    if (blk < 512) {
        const int n = blk;
        double s = 0.0;
        #pragma unroll
        for (int j = 0; j < 4; ++j) {
            int k = 1 + lane + 64 * j;               // 1..256
            double wk = (k < 256) ? 2.0 : 1.0;
            int m = (k * n) & 511;                   // exact phase reduction
            s += wk * (double)k * cos((double)m * (M_PI / 256.0));
        }
        for (int off = 1; off < 64; off <<= 1) s += __shfl_xor(s, off);
        if (lane == 0) ws[WS_HR + n] = (float)(s * (1.0 / 262144.0));
    } else {
        int a = (blk - 512) * 64 + lane;
        if (a < NANG) {
            double th = (double)a * (M_PI / 180.0);
            double sc = 255.5 / sqrt(2.0);
            ws[WS_CA + a] = (float)(cos(th) * sc);
            ws[WS_SA + a] = (float)(sin(th) * sc);
        }
    }
}

// ---------------- kernel 2: Ram-Lak filtering (circular conv) ----------------
// grid 360: blockIdx = a*2 + half ; block 256 threads.
// Each wave covers all 8 batches (b=lane&7) x 64 outputs; thread owns 8 consecutive outputs.
__device__ __forceinline__ int hswz(int s) {            // swizzled chunk slot
    return (s & 0x78) | ((s ^ (s >> 3)) & 7);
}

__global__ __launch_bounds__(256) void k_filter(const float* __restrict__ x, float* ws) {
    __shared__ float xs[8 * 516];      // 8 padded sinogram rows
    __shared__ float hrs[512];         // swizzled h chunks
    const int a    = blockIdx.x >> 1;
    const int half = blockIdx.x & 1;
    const int tid  = threadIdx.x;
    const int lane = tid & 63;
    const int wv   = tid >> 6;         // 0..3

    // stage h (swizzled)
    #pragma unroll
    for (int p = 0; p < 2; ++p) {
        int i = tid + 256 * p;
        int s = i >> 2, j = i & 3;
        hrs[hswz(s) * 4 + j] = ws[WS_HR + i];
    }
    // stage 8 sinogram rows for angle a (each 32-lane half-wave stages one row)
    {
        int b  = wv * 2 + (lane >> 5);
        int l5 = lane & 31;
        const float* xr = x + (b * NANG + a) * NDET;
        float* xd = xs + b * 516;
        #pragma unroll
        for (int p = 0; p < 4; ++p) {
            int idx = l5 * 4 + p * 128;
            *(float4*)(xd + idx) = *(const float4*)(xr + idx);
        }
    }
    __syncthreads();

    const int b  = lane & 7;
    const int t  = lane >> 3;
    const int n0 = half * 256 + wv * 64 + t * 8;
    const int q  = n0 >> 2;
    const float* xrow = xs + b * 516;

    float acc[8] = {0, 0, 0, 0, 0, 0, 0, 0};
    float win[12];
    {
        int s2 = (-q - 2) & 127;
        int s1 = (-q - 1) & 127;
        float4 h2 = *(const float4*)(hrs + hswz(s2) * 4);
        float4 h1 = *(const float4*)(hrs + hswz(s1) * 4);
        win[0] = h2.x; win[1] = h2.y; win[2]  = h2.z; win[3]  = h2.w;
        win[4] = h1.x; win[5] = h1.y; win[6]  = h1.z; win[7]  = h1.w;
    }
    #pragma unroll 2
    for (int c = 0; c < 128; ++c) {
        int s = (c - q) & 127;
        float4 hc = *(const float4*)(hrs + hswz(s) * 4);
        win[8] = hc.x; win[9] = hc.y; win[10] = hc.z; win[11] = hc.w;
        float4 xv = *(const float4*)(xrow + c * 4);
        float xa[4] = {xv.x, xv.y, xv.z, xv.w};
        #pragma unroll
        for (int k = 0; k < 8; ++k)
            #pragma unroll
            for (int j = 0; j < 4; ++j)
                acc[k] = fmaf(xa[j], win[8 + j - k], acc[k]);
        #pragma unroll
        for (int i2 = 0; i2 < 8; ++i2) win[i2] = win[i2 + 4];
    }
    // write fglob[a][n][b]
    float* fg = ws + WS_FG;
    #pragma unroll
    for (int k = 0; k < 8; ++k)
        fg[(a * NDET + n0 + k) * NB + b] = acc[k];
}

// ---------------- kernel 3: backprojection ----------------
// grid 256 (16x16 tile blocks of 32x32 px), block 1024. Double-buffered LDS,
// 2 angles per chunk, all 8 batches per thread.
__global__ __launch_bounds__(1024) void k_bp(float* ws) {
    __shared__ float4 smem4[4096];     // 64 KiB: 2 buf x 2 angles x 512 d x 8 b
    float* smem = (float*)smem4;
    const int tid  = threadIdx.x;
    const int wv   = tid >> 6, lane = tid & 63;
    const int bx   = blockIdx.x & 15, by = blockIdx.x >> 4;
    const int iy   = by * 32 + (wv >> 2) * 8 + (lane >> 3);
    const int ix   = bx * 32 + (wv & 3) * 8 + (lane & 7);
    const float xf = -1.0f + (float)ix * (2.0f / 511.0f);
    const float yf = -1.0f + (float)iy * (2.0f / 511.0f);

    const float* fg  = ws + WS_FG;
    const float* cav = ws + WS_CA;
    const float* sav = ws + WS_SA;

    float acc[8] = {0, 0, 0, 0, 0, 0, 0, 0};

    auto stage = [&](int bi, int ch) {
        const char* gp = (const char*)(fg + ch * 8192) + tid * 16;
        char* lp = (char*)(smem + bi * 8192) + tid * 16;
        gld_lds16(gp, lp);
        gld_lds16(gp + 16384, lp + 16384);
    };

    stage(0, 0);
    __syncthreads();

    for (int c = 0; c < 90; ++c) {
        if (c < 89) stage((c + 1) & 1, c + 1);
        const float* buf = smem + (c & 1) * 8192;
        #pragma unroll
        for (int j = 0; j < 2; ++j) {
            const int ang = 2 * c + j;
            const float ca = cav[ang], sa = sav[ang];
            const float* ab = buf + j * 4096;
            float u = fmaf(xf, ca, fmaf(yf, sa, 255.5f));
            u = fminf(fmaxf(u, 0.0f), 510.99996948f);
            float fi = floorf(u);
            float w  = u - fi;
            int  i0  = (int)fi;
            const float4* p = (const float4*)(ab + i0 * 8);
            float4 A0 = p[0], A1 = p[1], B0 = p[2], B1 = p[3];
            acc[0] = fmaf(w, B0.x - A0.x, acc[0] + A0.x);
            acc[1] = fmaf(w, B0.y - A0.y, acc[1] + A0.y);
            acc[2] = fmaf(w, B0.z - A0.z, acc[2] + A0.z);
            acc[3] = fmaf(w, B0.w - A0.w, acc[3] + A0.w);
            acc[4] = fmaf(w, B1.x - A1.x, acc[4] + A1.x);
            acc[5] = fmaf(w, B1.y - A1.y, acc[5] + A1.y);
            acc[6] = fmaf(w, B1.z - A1.z, acc[6] + A1.z);
            acc[7] = fmaf(w, B1.w - A1.w, acc[7] + A1.w);
        }
        __syncthreads();
    }

    const float scale = (float)((2.0 / 512.0) * M_PI / 180.0);
    float* bp = ws + WS_BP;
    #pragma unroll
    for (int b = 0; b < 8; ++b)
        bp[b * (NIMG * NIMG) + iy * NIMG + ix] = acc[b] * scale;
}

// ---------------- kernel 4: 3x3 gaussian blur + clip ----------------
__global__ __launch_bounds__(256) void k_blur(const float* __restrict__ ws, float* __restrict__ out) {
    const int gid = blockIdx.x * 256 + threadIdx.x;
    const int b  = gid >> 18;
    const int r  = (gid >> 9) & 511;
    const int cx = gid & 511;
    const float KA = 0.10650697891920077f;   // e^-2 / (1+2e^-2)
    const float KB = 0.78698604216159850f;   // 1 / (1+2e^-2)
    const float* img = ws + WS_BP + b * (NIMG * NIMG);
    const float* rp = img + r * 512 + cx;

    float rowm = 0.0f, row0, rowp = 0.0f;
    {
        float l = (cx > 0)   ? rp[-1] : 0.0f;
        float rr = (cx < 511) ? rp[1]  : 0.0f;
        row0 = KA * (l + rr) + KB * rp[0];
    }
    if (r > 0) {
        const float* q = rp - 512;
        float l = (cx > 0)   ? q[-1] : 0.0f;
        float rr = (cx < 511) ? q[1]  : 0.0f;
        rowm = KA * (l + rr) + KB * q[0];
    }
    if (r < 511) {
        const float* q = rp + 512;
        float l = (cx > 0)   ? q[-1] : 0.0f;
        float rr = (cx < 511) ? q[1]  : 0.0f;
        rowp = KA * (l + rr) + KB * q[0];
    }
    float v = KA * (rowm + rowp) + KB * row0;
    v = fminf(fmaxf(v, -1.0f), 1.0f);
    out[gid] = v;
}

extern "C" void kernel_launch(void* const* d_in, const int* in_sizes, int n_in,
                              void* d_out, int out_size, void* d_ws, size_t ws_size,
                              hipStream_t stream) {
    const float* x = (const float*)d_in[0];
    float* out = (float*)d_out;
    float* ws  = (float*)d_ws;

    k_tables<<<515, 64, 0, stream>>>(ws);
    k_filter<<<NANG * 2, 256, 0, stream>>>(x, ws);
    k_bp<<<256, 1024, 0, stream>>>(ws);
    k_blur<<<(NB * NIMG * NIMG) / 256, 256, 0, stream>>>(ws, out);
}

// Round 4
// 90.766 us; speedup vs baseline: 1.3862x; 1.3862x over previous
//
#include <hip/hip_runtime.h>
#include <math.h>

#define NDET 512
#define NANG 180
#define NB   8
#define NIMG 512

// ---- ws layout in floats ----
#define WS_HR   0                      // 512: Ram-Lak spatial kernel h
#define WS_CASA 512                    // 180 x float2 {ca,sa} = 360 floats
#define WS_CB   1024                   // cbtab[angle][block] = 180*256 floats
#define WS_FG   (1024 + NANG*256)      // fglob[a][d][b]: 180*512*8 floats
#define WS_BP   (WS_FG + NANG*NDET*NB) // bp image [8][512][512]

// ---------------- kernel 1: prep (h closed-form, angle tables, per-block cb) ----------------
// h[n] = (1/512^2) [ 2*sum_{k=1}^{255} k cos(pi k n/256) + 256 cos(pi n) ]
// sum_{k=1}^{m} k cos(k t) = ((m+1)cos(mt) - m cos((m+1)t) - 1)/(4 sin^2(t/2))
__global__ __launch_bounds__(256) void k_prep(float* ws) {
    const int blk = blockIdx.x, t = threadIdx.x;
    if (blk == 0) {
        #pragma unroll
        for (int p = 0; p < 2; ++p) {
            int n = t + 256 * p;
            float h;
            if (n == 0) h = 0.25f;
            else if ((n & 1) == 0) h = 0.0f;
            else {
                double th = (double)n * (M_PI / 256.0);
                double s2 = sin(0.5 * th);
                double S  = (254.0 - 256.0 * cos(th)) / (4.0 * s2 * s2);
                h = (float)((2.0 * S - 256.0) / 262144.0);
            }
            ws[WS_HR + n] = h;
        }
        if (t < NANG) {
            double th = (double)t * (M_PI / 180.0);
            double sc = 255.5 / sqrt(2.0);
            ws[WS_CASA + 2 * t]     = (float)(cos(th) * sc);
            ws[WS_CASA + 2 * t + 1] = (float)(sin(th) * sc);
        }
    } else {
        const int a = blk - 1;                     // angle 0..179
        double th = (double)a * (M_PI / 180.0);
        double sc = 255.5 / sqrt(2.0);
        const float ca = (float)(cos(th) * sc), sa = (float)(sin(th) * sc);
        const int bx = t & 15, by = t >> 4;        // t = image block id
        const float x0 = -1.f + (float)(bx * 32)      * (2.f / 511.f);
        const float x1 = -1.f + (float)(bx * 32 + 31) * (2.f / 511.f);
        const float y0 = -1.f + (float)(by * 32)      * (2.f / 511.f);
        const float y1 = -1.f + (float)(by * 32 + 31) * (2.f / 511.f);
        float u00 = fmaf(x0, ca, fmaf(y0, sa, 255.5f));
        float u01 = fmaf(x1, ca, fmaf(y0, sa, 255.5f));
        float u10 = fmaf(x0, ca, fmaf(y1, sa, 255.5f));
        float u11 = fmaf(x1, ca, fmaf(y1, sa, 255.5f));
        float umin = fminf(fminf(u00, u01), fminf(u10, u11));
        int d0 = (int)floorf(umin) - 1;
        d0 = max(0, min(476, d0));
        ws[WS_CB + a * 256 + t] = 255.5f - (float)d0;
    }
}

// ---------------- kernel 2: Ram-Lak filtering (circular conv) ----------------
__device__ __forceinline__ int hswz(int s) {            // swizzled chunk slot
    return (s & 0x78) | ((s ^ (s >> 3)) & 7);
}

__global__ __launch_bounds__(256) void k_filter(const float* __restrict__ x, float* ws) {
    __shared__ float xs[8 * 516];      // 8 padded sinogram rows
    __shared__ float hrs[512];         // swizzled h chunks
    const int a    = blockIdx.x >> 1;
    const int half = blockIdx.x & 1;
    const int tid  = threadIdx.x;
    const int lane = tid & 63;
    const int wv   = tid >> 6;         // 0..3

    #pragma unroll
    for (int p = 0; p < 2; ++p) {
        int i = tid + 256 * p;
        int s = i >> 2, j = i & 3;
        hrs[hswz(s) * 4 + j] = ws[WS_HR + i];
    }
    {
        int b  = wv * 2 + (lane >> 5);
        int l5 = lane & 31;
        const float* xr = x + (b * NANG + a) * NDET;
        float* xd = xs + b * 516;
        #pragma unroll
        for (int p = 0; p < 4; ++p) {
            int idx = l5 * 4 + p * 128;
            *(float4*)(xd + idx) = *(const float4*)(xr + idx);
        }
    }
    __syncthreads();

    const int b  = lane & 7;
    const int t  = lane >> 3;
    const int n0 = half * 256 + wv * 64 + t * 8;
    const int q  = n0 >> 2;
    const float* xrow = xs + b * 516;

    float acc[8] = {0, 0, 0, 0, 0, 0, 0, 0};
    float win[12];
    {
        int s2 = (-q - 2) & 127;
        int s1 = (-q - 1) & 127;
        float4 h2 = *(const float4*)(hrs + hswz(s2) * 4);
        float4 h1 = *(const float4*)(hrs + hswz(s1) * 4);
        win[0] = h2.x; win[1] = h2.y; win[2]  = h2.z; win[3]  = h2.w;
        win[4] = h1.x; win[5] = h1.y; win[6]  = h1.z; win[7]  = h1.w;
    }
    #pragma unroll 2
    for (int c = 0; c < 128; ++c) {
        int s = (c - q) & 127;
        float4 hc = *(const float4*)(hrs + hswz(s) * 4);
        win[8] = hc.x; win[9] = hc.y; win[10] = hc.z; win[11] = hc.w;
        float4 xv = *(const float4*)(xrow + c * 4);
        float xa[4] = {xv.x, xv.y, xv.z, xv.w};
        #pragma unroll
        for (int k = 0; k < 8; ++k)
            #pragma unroll
            for (int j = 0; j < 4; ++j)
                acc[k] = fmaf(xa[j], win[8 + j - k], acc[k]);
        #pragma unroll
        for (int i2 = 0; i2 < 8; ++i2) win[i2] = win[i2 + 4];
    }
    float* fg = ws + WS_FG;
    #pragma unroll
    for (int k = 0; k < 8; ++k)
        fg[(a * NDET + n0 + k) * NB + b] = acc[k];
}

// ---------------- kernel 3: backprojection (windowed LDS, 2 chunks of 90 angles) ----------------
// Each block: 32x32 px tile. Per angle only a 36-det window [d0, d0+35] is staged:
// win[90][36][8] floats = 103,680 B LDS. 3 barriers total.
#define WWIN   36
#define CHANG  90
#define CHUNK16 ((CHANG * WWIN * NB * 4) / 16)   // 6480 16B-chunks per chunk
#define F4PA   (WWIN * NB / 4)                   // 72 float4 per angle

__global__ __launch_bounds__(1024) void k_bp(float* ws) {
    __shared__ float win[CHANG * WWIN * NB];     // 103,680 B
    const int tid  = threadIdx.x;
    const int wv   = tid >> 6, lane = tid & 63;
    const int bid  = blockIdx.x;
    const int bx   = bid & 15, by = bid >> 4;
    const int iy   = by * 32 + (wv >> 2) * 8 + (lane >> 3);
    const int ix   = bx * 32 + (wv & 3) * 8 + (lane & 7);
    const float xf = -1.0f + (float)ix * (2.0f / 511.0f);
    const float yf = -1.0f + (float)iy * (2.0f / 511.0f);

    const float* __restrict__ fg   = ws + WS_FG;
    const float* __restrict__ cbt  = ws + WS_CB;
    const float* __restrict__ casa = ws + WS_CASA;

    float acc[8] = {0, 0, 0, 0, 0, 0, 0, 0};

    // load one chunk's window data into registers (7 float4 per thread)
    auto ld_chunk = [&](int ch, float4* f4) {
        #pragma unroll
        for (int r = 0; r < 7; ++r) {
            int c = r * 1024 + tid;
            if (c < CHUNK16) {
                unsigned a = (unsigned)c / (unsigned)F4PA;       // 0..89
                int o  = c - (int)a * F4PA;                      // 0..71
                int ag = ch * CHANG + (int)a;
                float cb = cbt[ag * 256 + bid];
                int d0 = (int)(255.5f - cb);
                f4[r] = *(const float4*)(fg + (ag * (NDET * NB) + d0 * NB + o * 4));
            }
        }
    };
    auto wr_chunk = [&](const float4* f4) {
        #pragma unroll
        for (int r = 0; r < 7; ++r) {
            int c = r * 1024 + tid;
            if (c < CHUNK16) *(float4*)((char*)win + c * 16) = f4[r];
        }
    };
    auto comp = [&](int ch) {
        #pragma unroll 2
        for (int al = 0; al < CHANG; ++al) {
            const int ag = ch * CHANG + al;                       // uniform -> s_load
            const float2 cs = *(const float2*)(casa + 2 * ag);
            const float  cb = cbt[ag * 256 + bid];
            float v = fmaf(xf, cs.x, fmaf(yf, cs.y, cb));
            v = fminf(fmaxf(v, 0.0f), 34.99996948f);
            float fj = floorf(v);
            float w  = v - fj;
            int j0   = (int)fj;
            const float* p = win + (al * (WWIN * NB) + j0 * NB);
            float4 A0 = *(const float4*)p,       A1 = *(const float4*)(p + 4);
            float4 B0 = *(const float4*)(p + 8), B1 = *(const float4*)(p + 12);
            acc[0] = fmaf(w, B0.x - A0.x, acc[0] + A0.x);
            acc[1] = fmaf(w, B0.y - A0.y, acc[1] + A0.y);
            acc[2] = fmaf(w, B0.z - A0.z, acc[2] + A0.z);
            acc[3] = fmaf(w, B0.w - A0.w, acc[3] + A0.w);
            acc[4] = fmaf(w, B1.x - A1.x, acc[4] + A1.x);
            acc[5] = fmaf(w, B1.y - A1.y, acc[5] + A1.y);
            acc[6] = fmaf(w, B1.z - A1.z, acc[6] + A1.z);
            acc[7] = fmaf(w, B1.w - A1.w, acc[7] + A1.w);
        }
    };

    float4 f4a[7], f4b[7];
    ld_chunk(0, f4a);
    wr_chunk(f4a);
    ld_chunk(1, f4b);          // prefetch chunk 1 into registers
    __syncthreads();
    comp(0);
    __syncthreads();
    wr_chunk(f4b);
    __syncthreads();
    comp(1);

    const float scale = (float)((2.0 / 512.0) * M_PI / 180.0);
    float* bp = ws + WS_BP;
    #pragma unroll
    for (int b = 0; b < 8; ++b)
        bp[b * (NIMG * NIMG) + iy * NIMG + ix] = acc[b] * scale;
}

// ---------------- kernel 4: 3x3 gaussian blur + clip ----------------
__global__ __launch_bounds__(256) void k_blur(const float* __restrict__ ws, float* __restrict__ out) {
    const int gid = blockIdx.x * 256 + threadIdx.x;
    const int b  = gid >> 18;
    const int r  = (gid >> 9) & 511;
    const int cx = gid & 511;
    const float KA = 0.10650697891920077f;   // e^-2 / (1+2e^-2)
    const float KB = 0.78698604216159850f;   // 1 / (1+2e^-2)
    const float* img = ws + WS_BP + b * (NIMG * NIMG);
    const float* rp = img + r * 512 + cx;

    float rowm = 0.0f, row0, rowp = 0.0f;
    {
        float l  = (cx > 0)   ? rp[-1] : 0.0f;
        float rr = (cx < 511) ? rp[1]  : 0.0f;
        row0 = KA * (l + rr) + KB * rp[0];
    }
    if (r > 0) {
        const float* q = rp - 512;
        float l  = (cx > 0)   ? q[-1] : 0.0f;
        float rr = (cx < 511) ? q[1]  : 0.0f;
        rowm = KA * (l + rr) + KB * q[0];
    }
    if (r < 511) {
        const float* q = rp + 512;
        float l  = (cx > 0)   ? q[-1] : 0.0f;
        float rr = (cx < 511) ? q[1]  : 0.0f;
        rowp = KA * (l + rr) + KB * q[0];
    }
    float v = KA * (rowm + rowp) + KB * row0;
    v = fminf(fmaxf(v, -1.0f), 1.0f);
    out[gid] = v;
}

extern "C" void kernel_launch(void* const* d_in, const int* in_sizes, int n_in,
                              void* d_out, int out_size, void* d_ws, size_t ws_size,
                              hipStream_t stream) {
    const float* x = (const float*)d_in[0];
    float* out = (float*)d_out;
    float* ws  = (float*)d_ws;

    k_prep<<<1 + NANG, 256, 0, stream>>>(ws);
    k_filter<<<NANG * 2, 256, 0, stream>>>(x, ws);
    k_bp<<<256, 1024, 0, stream>>>(ws);
    k_blur<<<(NB * NIMG * NIMG) / 256, 256, 0, stream>>>(ws, out);
}

// Round 5
// 86.304 us; speedup vs baseline: 1.4578x; 1.0517x over previous
//
#include <hip/hip_runtime.h>
#include <hip/hip_fp16.h>
#include <math.h>

#define NDET 512
#define NANG 180
#define NB   8
#define NIMG 512

// ---- ws layout in floats ----
#define WS_CASA 0                      // 180 x {ca,sa} = 360 floats
#define WS_CBT  360                    // cbt[block][angle] = 256*180 floats
#define WS_FGH  46464                  // fgh[a][d][b] halves: 180*512*8*2B = 368,640 floats
#define WS_BP   (46464 + 368640)       // bp image [8][512][512] fp32

__device__ __forceinline__ void gld_lds16(const void* g, void* l) {
    __builtin_amdgcn_global_load_lds((__attribute__((address_space(1))) void*)g,
                                     (__attribute__((address_space(3))) void*)l,
                                     16, 0, 0);
}

__device__ __forceinline__ int hswz(int s) {            // swizzled h-chunk slot
    return (s & 0x78) | ((s ^ (s >> 3)) & 7);
}

// ---------------- kernel 1: Ram-Lak filter (h inline) + tables + fp16 store ----------------
// grid 360: blockIdx = a*2 + half ; 256 threads.
// h[n] closed form: for odd n, S = (254-256cos(th))/(4 sin^2(th/2)), h=(2S-256)/512^2;
// h[0]=0.25, even n -> 0.  (Verified against irfft(rfftfreq(512)).)
__global__ __launch_bounds__(256) void k_filter(const float* __restrict__ x, float* ws) {
    __shared__ float xs[8 * 516];      // 8 padded sinogram rows
    __shared__ float hrs[512];         // swizzled h chunks
    const int a     = blockIdx.x >> 1;
    const int half_ = blockIdx.x & 1;
    const int tid   = threadIdx.x;
    const int lane  = tid & 63;
    const int wv    = tid >> 6;        // 0..3

    // compute h inline (closed form) into swizzled LDS
    #pragma unroll
    for (int p = 0; p < 2; ++p) {
        int n = tid + 256 * p;
        float h;
        if (n == 0) h = 0.25f;
        else if ((n & 1) == 0) h = 0.0f;
        else {
            double th = (double)n * (M_PI / 256.0);
            double s2 = sin(0.5 * th);
            double S  = (254.0 - 256.0 * cos(th)) / (4.0 * s2 * s2);
            h = (float)((2.0 * S - 256.0) / 262144.0);
        }
        hrs[hswz(n >> 2) * 4 + (n & 3)] = h;
    }
    // stage 8 sinogram rows for angle a
    {
        int b  = wv * 2 + (lane >> 5);
        int l5 = lane & 31;
        const float* xr = x + (b * NANG + a) * NDET;
        float* xd = xs + b * 516;
        #pragma unroll
        for (int p = 0; p < 4; ++p) {
            int idx = l5 * 4 + p * 128;
            *(float4*)(xd + idx) = *(const float4*)(xr + idx);
        }
    }
    // angle tables + per-(block,angle) window base (only half_==0 blocks)
    if (half_ == 0) {
        double th = (double)a * (M_PI / 180.0);
        double sc = 255.5 / sqrt(2.0);
        const float ca = (float)(cos(th) * sc), sa = (float)(sin(th) * sc);
        if (tid == 0) {
            ws[WS_CASA + 2 * a]     = ca;
            ws[WS_CASA + 2 * a + 1] = sa;
        }
        const int bx = tid & 15, by = tid >> 4;        // tid = image block id
        const float x0 = -1.f + (float)(bx * 32)      * (2.f / 511.f);
        const float x1 = -1.f + (float)(bx * 32 + 31) * (2.f / 511.f);
        const float y0 = -1.f + (float)(by * 32)      * (2.f / 511.f);
        const float y1 = -1.f + (float)(by * 32 + 31) * (2.f / 511.f);
        float u00 = fmaf(x0, ca, fmaf(y0, sa, 255.5f));
        float u01 = fmaf(x1, ca, fmaf(y0, sa, 255.5f));
        float u10 = fmaf(x0, ca, fmaf(y1, sa, 255.5f));
        float u11 = fmaf(x1, ca, fmaf(y1, sa, 255.5f));
        float umin = fminf(fminf(u00, u01), fminf(u10, u11));
        int d0 = (int)floorf(umin) - 1;
        d0 = max(0, min(476, d0));
        ws[WS_CBT + tid * 180 + a] = 255.5f - (float)d0;
    }
    __syncthreads();

    const int b  = lane & 7;
    const int t  = lane >> 3;
    const int n0 = half_ * 256 + wv * 64 + t * 8;
    const int q  = n0 >> 2;
    const float* xrow = xs + b * 516;

    float acc[8] = {0, 0, 0, 0, 0, 0, 0, 0};
    float win[12];
    {
        int s2 = (-q - 2) & 127;
        int s1 = (-q - 1) & 127;
        float4 h2 = *(const float4*)(hrs + hswz(s2) * 4);
        float4 h1 = *(const float4*)(hrs + hswz(s1) * 4);
        win[0] = h2.x; win[1] = h2.y; win[2]  = h2.z; win[3]  = h2.w;
        win[4] = h1.x; win[5] = h1.y; win[6]  = h1.z; win[7]  = h1.w;
    }
    #pragma unroll 2
    for (int c = 0; c < 128; ++c) {
        int s = (c - q) & 127;
        float4 hc = *(const float4*)(hrs + hswz(s) * 4);
        win[8] = hc.x; win[9] = hc.y; win[10] = hc.z; win[11] = hc.w;
        float4 xv = *(const float4*)(xrow + c * 4);
        float xa[4] = {xv.x, xv.y, xv.z, xv.w};
        #pragma unroll
        for (int k = 0; k < 8; ++k)
            #pragma unroll
            for (int j = 0; j < 4; ++j)
                acc[k] = fmaf(xa[j], win[8 + j - k], acc[k]);
        #pragma unroll
        for (int i2 = 0; i2 < 8; ++i2) win[i2] = win[i2 + 4];
    }
    __half* fgh = (__half*)(ws + WS_FGH);
    #pragma unroll
    for (int k = 0; k < 8; ++k)
        fgh[(a * NDET + n0 + k) * NB + b] = __float2half(acc[k]);
}

// ---------------- kernel 2: backprojection (fp16 windows, single barrier) ----------------
// Block = 32x32 px tile. All 180 angle-windows (36 dets x 8 batches, fp16) staged at once:
// 180*36*16B = 103,680 B LDS, via global_load_lds. Then one compute sweep.
#define WWIN 36
#define NCHK (NANG * WWIN)             // 6480 16B chunks

__global__ __launch_bounds__(1024) void k_bp(float* ws) {
    __shared__ uint4 win4[NCHK];       // 103,680 B
    const int tid  = threadIdx.x;
    const int wv   = tid >> 6, lane = tid & 63;
    const int bid  = blockIdx.x;
    const int bx   = bid & 15, by = bid >> 4;
    const int iy   = by * 32 + (wv >> 2) * 8 + (lane >> 3);
    const int ix   = bx * 32 + (wv & 3) * 8 + (lane & 7);
    const float xf = -1.0f + (float)ix * (2.0f / 511.0f);
    const float yf = -1.0f + (float)iy * (2.0f / 511.0f);

    const __half* __restrict__ fgh  = (const __half*)(ws + WS_FGH);
    const float*  __restrict__ cbt  = ws + WS_CBT + bid * 180;   // this block's column
    const float*  __restrict__ casa = ws + WS_CASA;

    // stage all 180 windows: chunk c -> angle a=c/36, det d0[a]+o, o=c%36
    #pragma unroll
    for (int r = 0; r < 7; ++r) {
        int c = r * 1024 + tid;
        if (c < NCHK) {
            unsigned a = (unsigned)c / 36u;
            int o  = c - (int)a * 36;
            float cb = cbt[a];
            int d0 = (int)(255.5f - cb);
            gld_lds16(fgh + ((int)a * NDET + d0 + o) * NB, win4 + c);
        }
    }
    __syncthreads();

    float acc[8] = {0, 0, 0, 0, 0, 0, 0, 0};
    #pragma unroll 2
    for (int al = 0; al < NANG; ++al) {
        const float2 cs = *(const float2*)(casa + 2 * al);   // uniform -> s_load
        const float  cb = cbt[al];                           // uniform -> s_load
        float v = fmaf(xf, cs.x, fmaf(yf, cs.y, cb));
        v = fminf(fmaxf(v, 0.0f), 34.99996948f);
        float fj = floorf(v);
        float w  = v - fj;
        int  j0  = (int)fj;
        const char* pc = (const char*)win4 + al * (WWIN * 16) + (j0 << 4);
        uint4 da = *(const uint4*)pc;            // det j0:   batches 0..7 (4x half2)
        uint4 db = *(const uint4*)(pc + 16);     // det j0+1: batches 0..7
        __half2 w2 = __float2half2_rn(w);
        __half2 a0 = __builtin_bit_cast(__half2, da.x), b0 = __builtin_bit_cast(__half2, db.x);
        __half2 a1 = __builtin_bit_cast(__half2, da.y), b1 = __builtin_bit_cast(__half2, db.y);
        __half2 a2 = __builtin_bit_cast(__half2, da.z), b2 = __builtin_bit_cast(__half2, db.z);
        __half2 a3 = __builtin_bit_cast(__half2, da.w), b3 = __builtin_bit_cast(__half2, db.w);
        float2 f0 = __half22float2(__hfma2(w2, __hsub2(b0, a0), a0));
        float2 f1 = __half22float2(__hfma2(w2, __hsub2(b1, a1), a1));
        float2 f2 = __half22float2(__hfma2(w2, __hsub2(b2, a2), a2));
        float2 f3 = __half22float2(__hfma2(w2, __hsub2(b3, a3), a3));
        acc[0] += f0.x; acc[1] += f0.y;
        acc[2] += f1.x; acc[3] += f1.y;
        acc[4] += f2.x; acc[5] += f2.y;
        acc[6] += f3.x; acc[7] += f3.y;
    }

    const float scale = (float)((2.0 / 512.0) * M_PI / 180.0);
    float* bp = ws + WS_BP;
    #pragma unroll
    for (int b = 0; b < 8; ++b)
        bp[b * (NIMG * NIMG) + iy * NIMG + ix] = acc[b] * scale;
}

// ---------------- kernel 3: 3x3 gaussian blur + clip ----------------
__global__ __launch_bounds__(256) void k_blur(const float* __restrict__ ws, float* __restrict__ out) {
    const int gid = blockIdx.x * 256 + threadIdx.x;
    const int b  = gid >> 18;
    const int r  = (gid >> 9) & 511;
    const int cx = gid & 511;
    const float KA = 0.10650697891920077f;   // e^-2 / (1+2e^-2)
    const float KB = 0.78698604216159850f;   // 1 / (1+2e^-2)
    const float* img = ws + WS_BP + b * (NIMG * NIMG);
    const float* rp = img + r * 512 + cx;

    float rowm = 0.0f, row0, rowp = 0.0f;
    {
        float l  = (cx > 0)   ? rp[-1] : 0.0f;
        float rr = (cx < 511) ? rp[1]  : 0.0f;
        row0 = KA * (l + rr) + KB * rp[0];
    }
    if (r > 0) {
        const float* q = rp - 512;
        float l  = (cx > 0)   ? q[-1] : 0.0f;
        float rr = (cx < 511) ? q[1]  : 0.0f;
        rowm = KA * (l + rr) + KB * q[0];
    }
    if (r < 511) {
        const float* q = rp + 512;
        float l  = (cx > 0)   ? q[-1] : 0.0f;
        float rr = (cx < 511) ? q[1]  : 0.0f;
        rowp = KA * (l + rr) + KB * q[0];
    }
    float v = KA * (rowm + rowp) + KB * row0;
    v = fminf(fmaxf(v, -1.0f), 1.0f);
    out[gid] = v;
}

extern "C" void kernel_launch(void* const* d_in, const int* in_sizes, int n_in,
                              void* d_out, int out_size, void* d_ws, size_t ws_size,
                              hipStream_t stream) {
    const float* x = (const float*)d_in[0];
    float* out = (float*)d_out;
    float* ws  = (float*)d_ws;

    k_filter<<<NANG * 2, 256, 0, stream>>>(x, ws);
    k_bp<<<256, 1024, 0, stream>>>(ws);
    k_blur<<<(NB * NIMG * NIMG) / 256, 256, 0, stream>>>(ws, out);
}

// Round 8
// 77.905 us; speedup vs baseline: 1.6150x; 1.1078x over previous
//
#include <hip/hip_runtime.h>
#include <hip/hip_fp16.h>
#include <math.h>

#define NDET 512
#define NANG 180
#define NB   8
#define NIMG 512

// ---- ws layout in floats ----
#define WS_CASA 0                      // 180 x {ca,sa} = 360 floats
#define WS_CBT  360                    // cbt[block][angle] = 256*180 floats
#define WS_FGH  46464                  // fgh[a][d][b] halves: 180*512*8*2B = 368,640 floats
#define WS_BP   (46464 + 368640)       // bp image [8][512][512] fp32

typedef _Float16 h2_t __attribute__((ext_vector_type(2)));

__device__ __forceinline__ void gld_lds16(const void* g, void* l) {
    __builtin_amdgcn_global_load_lds((__attribute__((address_space(1))) void*)g,
                                     (__attribute__((address_space(3))) void*)l,
                                     16, 0, 0);
}

__device__ __forceinline__ int hswz(int s) {            // swizzled h-chunk slot
    return (s & 0x78) | ((s ^ (s >> 3)) & 7);
}

// ---------------- kernel 1: Ram-Lak filter (h inline) + tables + fp16 store ----------------
__global__ __launch_bounds__(256) void k_filter(const float* __restrict__ x, float* ws) {
    __shared__ float xs[8 * 516];      // 8 padded sinogram rows
    __shared__ float hrs[512];         // swizzled h chunks
    const int a     = blockIdx.x >> 1;
    const int half_ = blockIdx.x & 1;
    const int tid   = threadIdx.x;
    const int lane  = tid & 63;
    const int wv    = tid >> 6;        // 0..3

    // compute h inline (closed form) into swizzled LDS
    #pragma unroll
    for (int p = 0; p < 2; ++p) {
        int n = tid + 256 * p;
        float h;
        if (n == 0) h = 0.25f;
        else if ((n & 1) == 0) h = 0.0f;
        else {
            double th = (double)n * (M_PI / 256.0);
            double s2 = sin(0.5 * th);
            double S  = (254.0 - 256.0 * cos(th)) / (4.0 * s2 * s2);
            h = (float)((2.0 * S - 256.0) / 262144.0);
        }
        hrs[hswz(n >> 2) * 4 + (n & 3)] = h;
    }
    // stage 8 sinogram rows for angle a
    {
        int b  = wv * 2 + (lane >> 5);
        int l5 = lane & 31;
        const float* xr = x + (b * NANG + a) * NDET;
        float* xd = xs + b * 516;
        #pragma unroll
        for (int p = 0; p < 4; ++p) {
            int idx = l5 * 4 + p * 128;
            *(float4*)(xd + idx) = *(const float4*)(xr + idx);
        }
    }
    // angle tables + per-(block,angle) window base (only half_==0 blocks)
    if (half_ == 0) {
        double th = (double)a * (M_PI / 180.0);
        double sc = 255.5 / sqrt(2.0);
        const float ca = (float)(cos(th) * sc), sa = (float)(sin(th) * sc);
        if (tid == 0) {
            ws[WS_CASA + 2 * a]     = ca;
            ws[WS_CASA + 2 * a + 1] = sa;
        }
        const int bx = tid & 15, by = tid >> 4;        // tid = image block id
        const float x0 = -1.f + (float)(bx * 32)      * (2.f / 511.f);
        const float x1 = -1.f + (float)(bx * 32 + 31) * (2.f / 511.f);
        const float y0 = -1.f + (float)(by * 32)      * (2.f / 511.f);
        const float y1 = -1.f + (float)(by * 32 + 31) * (2.f / 511.f);
        float u00 = fmaf(x0, ca, fmaf(y0, sa, 255.5f));
        float u01 = fmaf(x1, ca, fmaf(y0, sa, 255.5f));
        float u10 = fmaf(x0, ca, fmaf(y1, sa, 255.5f));
        float u11 = fmaf(x1, ca, fmaf(y1, sa, 255.5f));
        float umin = fminf(fminf(u00, u01), fminf(u10, u11));
        int d0 = (int)floorf(umin) - 1;
        d0 = max(0, min(476, d0));
        ws[WS_CBT + tid * 180 + a] = 255.5f - (float)d0;
    }
    __syncthreads();

    const int b  = lane & 7;
    const int t  = lane >> 3;
    const int n0 = half_ * 256 + wv * 64 + t * 8;
    const int q  = n0 >> 2;
    const float* xrow = xs + b * 516;

    float acc[8] = {0, 0, 0, 0, 0, 0, 0, 0};
    float win[12];
    {
        int s2 = (-q - 2) & 127;
        int s1 = (-q - 1) & 127;
        float4 h2 = *(const float4*)(hrs + hswz(s2) * 4);
        float4 h1 = *(const float4*)(hrs + hswz(s1) * 4);
        win[0] = h2.x; win[1] = h2.y; win[2]  = h2.z; win[3]  = h2.w;
        win[4] = h1.x; win[5] = h1.y; win[6]  = h1.z; win[7]  = h1.w;
    }
    #pragma unroll 2
    for (int c = 0; c < 128; ++c) {
        int s = (c - q) & 127;
        float4 hc = *(const float4*)(hrs + hswz(s) * 4);
        win[8] = hc.x; win[9] = hc.y; win[10] = hc.z; win[11] = hc.w;
        float4 xv = *(const float4*)(xrow + c * 4);
        float xa[4] = {xv.x, xv.y, xv.z, xv.w};
        #pragma unroll
        for (int k = 0; k < 8; ++k)
            #pragma unroll
            for (int j = 0; j < 4; ++j)
                acc[k] = fmaf(xa[j], win[8 + j - k], acc[k]);
        #pragma unroll
        for (int i2 = 0; i2 < 8; ++i2) win[i2] = win[i2 + 4];
    }
    __half* fgh = (__half*)(ws + WS_FGH);
    #pragma unroll
    for (int k = 0; k < 8; ++k)
        fgh[(a * NDET + n0 + k) * NB + b] = __float2half(acc[k]);
}

// ---------------- kernel 2: backprojection (fp16 windows, perm+dot2 interp) ----------------
#define WWIN 36
#define NCHK (NANG * WWIN)             // 6480 16B chunks

__global__ __launch_bounds__(1024) void k_bp(float* ws) {
    __shared__ uint4 win4[NCHK];       // 103,680 B
    const int tid  = threadIdx.x;
    const int wv   = tid >> 6, lane = tid & 63;
    const int bid  = blockIdx.x;
    const int bx   = bid & 15, by = bid >> 4;
    const int iy   = by * 32 + (wv >> 2) * 8 + (lane >> 3);
    const int ix   = bx * 32 + (wv & 3) * 8 + (lane & 7);
    const float xf = -1.0f + (float)ix * (2.0f / 511.0f);
    const float yf = -1.0f + (float)iy * (2.0f / 511.0f);

    const __half* __restrict__ fgh  = (const __half*)(ws + WS_FGH);
    const float*  __restrict__ cbt  = ws + WS_CBT + bid * 180;   // this block's column
    const float*  __restrict__ casa = ws + WS_CASA;

    // stage all 180 windows: chunk c -> angle a=c/36, det d0[a]+o, o=c%36
    #pragma unroll
    for (int r = 0; r < 7; ++r) {
        int c = r * 1024 + tid;
        if (c < NCHK) {
            unsigned a = (unsigned)c / 36u;
            int o  = c - (int)a * 36;
            float cb = cbt[a];
            int d0 = (int)(255.5f - cb);
            gld_lds16(fgh + ((int)a * NDET + d0 + o) * NB, win4 + c);
        }
    }
    __syncthreads();

    float acc[8] = {0, 0, 0, 0, 0, 0, 0, 0};
    #pragma unroll 4
    for (int al = 0; al < NANG; ++al) {
        const float2 cs = *(const float2*)(casa + 2 * al);   // uniform -> s_load
        const float  cb = cbt[al];                           // uniform -> s_load
        float v = fmaf(xf, cs.x, fmaf(yf, cs.y, cb));
        v = __builtin_amdgcn_fmed3f(v, 0.0f, 34.99996948f);
        float fj = floorf(v);
        float w  = v - fj;
        int  j0  = (int)fj;
        const char* pc = (const char*)win4 + al * (WWIN * 16) + (j0 << 4);
        uint4 da = *(const uint4*)pc;            // det j0:   batches 0..7 (4x half2)
        uint4 db = *(const uint4*)(pc + 16);     // det j0+1: batches 0..7
#if __has_builtin(__builtin_amdgcn_fdot2) && __has_builtin(__builtin_amdgcn_perm) && __has_builtin(__builtin_amdgcn_cvt_pkrtz)
        h2_t wp = __builtin_bit_cast(h2_t, __builtin_amdgcn_cvt_pkrtz(1.0f - w, w)); // half2(1-w, w)
        unsigned pl0 = __builtin_amdgcn_perm(db.x, da.x, 0x05040100u); // (A lo, B lo)
        unsigned ph0 = __builtin_amdgcn_perm(db.x, da.x, 0x07060302u); // (A hi, B hi)
        unsigned pl1 = __builtin_amdgcn_perm(db.y, da.y, 0x05040100u);
        unsigned ph1 = __builtin_amdgcn_perm(db.y, da.y, 0x07060302u);
        unsigned pl2 = __builtin_amdgcn_perm(db.z, da.z, 0x05040100u);
        unsigned ph2 = __builtin_amdgcn_perm(db.z, da.z, 0x07060302u);
        unsigned pl3 = __builtin_amdgcn_perm(db.w, da.w, 0x05040100u);
        unsigned ph3 = __builtin_amdgcn_perm(db.w, da.w, 0x07060302u);
        acc[0] = __builtin_amdgcn_fdot2(__builtin_bit_cast(h2_t, pl0), wp, acc[0], false);
        acc[1] = __builtin_amdgcn_fdot2(__builtin_bit_cast(h2_t, ph0), wp, acc[1], false);
        acc[2] = __builtin_amdgcn_fdot2(__builtin_bit_cast(h2_t, pl1), wp, acc[2], false);
        acc[3] = __builtin_amdgcn_fdot2(__builtin_bit_cast(h2_t, ph1), wp, acc[3], false);
        acc[4] = __builtin_amdgcn_fdot2(__builtin_bit_cast(h2_t, pl2), wp, acc[4], false);
        acc[5] = __builtin_amdgcn_fdot2(__builtin_bit_cast(h2_t, ph2), wp, acc[5], false);
        acc[6] = __builtin_amdgcn_fdot2(__builtin_bit_cast(h2_t, pl3), wp, acc[6], false);
        acc[7] = __builtin_amdgcn_fdot2(__builtin_bit_cast(h2_t, ph3), wp, acc[7], false);
#else
        __half2 w2 = __float2half2_rn(w);
        __half2 a0 = __builtin_bit_cast(__half2, da.x), b0 = __builtin_bit_cast(__half2, db.x);
        __half2 a1 = __builtin_bit_cast(__half2, da.y), b1 = __builtin_bit_cast(__half2, db.y);
        __half2 a2 = __builtin_bit_cast(__half2, da.z), b2 = __builtin_bit_cast(__half2, db.z);
        __half2 a3 = __builtin_bit_cast(__half2, da.w), b3 = __builtin_bit_cast(__half2, db.w);
        float2 f0 = __half22float2(__hfma2(w2, __hsub2(b0, a0), a0));
        float2 f1 = __half22float2(__hfma2(w2, __hsub2(b1, a1), a1));
        float2 f2 = __half22float2(__hfma2(w2, __hsub2(b2, a2), a2));
        float2 f3 = __half22float2(__hfma2(w2, __hsub2(b3, a3), a3));
        acc[0] += f0.x; acc[1] += f0.y;
        acc[2] += f1.x; acc[3] += f1.y;
        acc[4] += f2.x; acc[5] += f2.y;
        acc[6] += f3.x; acc[7] += f3.y;
#endif
    }

    const float scale = (float)((2.0 / 512.0) * M_PI / 180.0);
    float* bp = ws + WS_BP;
    #pragma unroll
    for (int b = 0; b < 8; ++b)
        bp[b * (NIMG * NIMG) + iy * NIMG + ix] = acc[b] * scale;
}

// ---------------- kernel 3: 3x3 gaussian blur + clip ----------------
__global__ __launch_bounds__(256) void k_blur(const float* __restrict__ ws, float* __restrict__ out) {
    const int gid = blockIdx.x * 256 + threadIdx.x;
    const int b  = gid >> 18;
    const int r  = (gid >> 9) & 511;
    const int cx = gid & 511;
    const float KA = 0.10650697891920077f;   // e^-2 / (1+2e^-2)
    const float KB = 0.78698604216159850f;   // 1 / (1+2e^-2)
    const float* img = ws + WS_BP + b * (NIMG * NIMG);
    const float* rp = img + r * 512 + cx;

    float rowm = 0.0f, row0, rowp = 0.0f;
    {
        float l  = (cx > 0)   ? rp[-1] : 0.0f;
        float rr = (cx < 511) ? rp[1]  : 0.0f;
        row0 = KA * (l + rr) + KB * rp[0];
    }
    if (r > 0) {
        const float* q = rp - 512;
        float l  = (cx > 0)   ? q[-1] : 0.0f;
        float rr = (cx < 511) ? q[1]  : 0.0f;
        rowm = KA * (l + rr) + KB * q[0];
    }
    if (r < 511) {
        const float* q = rp + 512;
        float l  = (cx > 0)   ? q[-1] : 0.0f;
        float rr = (cx < 511) ? q[1]  : 0.0f;
        rowp = KA * (l + rr) + KB * q[0];
    }
    float v = KA * (rowm + rowp) + KB * row0;
    v = fminf(fmaxf(v, -1.0f), 1.0f);
    out[gid] = v;
}

extern "C" void kernel_launch(void* const* d_in, const int* in_sizes, int n_in,
                              void* d_out, int out_size, void* d_ws, size_t ws_size,
                              hipStream_t stream) {
    const float* x = (const float*)d_in[0];
    float* out = (float*)d_out;
    float* ws  = (float*)d_ws;

    k_filter<<<NANG * 2, 256, 0, stream>>>(x, ws);
    k_bp<<<256, 1024, 0, stream>>>(ws);
    k_blur<<<(NB * NIMG * NIMG) / 256, 256, 0, stream>>>(ws, out);
}